// Round 5
// baseline (627.130 us; speedup 1.0000x reference)
//
#include <hip/hip_runtime.h>
#include <hip/hip_bf16.h>
#include <math.h>

#define N_ATOMS 500000
#define EPS 1e-5f

// wave counts per degree segment (8192 waves = 2048 blocks x 4 waves),
// proportional to gather volume n_d*(d+1)
#define NW1 443
#define NW2 1993
#define NW3 3543
#define NW4 2213
#define TOTW 8192
#define NBLK 2048

#define SEG_ELEMS 36864   // 288*128 bf16 per packed weight segment

typedef __attribute__((ext_vector_type(8))) short short8;
typedef __attribute__((ext_vector_type(4))) float floatx4;

__device__ __forceinline__ unsigned short f2bf(float f) {
    unsigned int x = __float_as_uint(f);
    x += 0x7FFF + ((x >> 16) & 1);          // round-to-nearest-even
    return (unsigned short)(x >> 16);
}

__device__ __forceinline__ short8 cvt8(float4 x0, float4 x1) {
    short8 v;
    v[0] = (short)f2bf(x0.x); v[1] = (short)f2bf(x0.y);
    v[2] = (short)f2bf(x0.z); v[3] = (short)f2bf(x0.w);
    v[4] = (short)f2bf(x1.x); v[5] = (short)f2bf(x1.y);
    v[6] = (short)f2bf(x1.z); v[7] = (short)f2bf(x1.w);
    return v;
}

__device__ __forceinline__ float4 add4(float4 a, float4 b) {
    return make_float4(a.x + b.x, a.y + b.y, a.z + b.z, a.w + b.w);
}

// ---------------------------------------------------------------------------
// Pack weights into MFMA B-fragment layout, bf16.
// K layout: [self 0..127 -> Wself[k] | a_sum 128..255 -> Wd[k-128] |
//            b_sum 256..271 -> Wd[k-128] | 272..287 -> 0]
// packed[d]: (ks 0..8, nt 0..7, lane 0..63) -> short8; col = nt*16+(lane&15),
// k = ks*32 + (lane>>4)*8 + j.
// ---------------------------------------------------------------------------
__global__ __launch_bounds__(256) void gdc_pack(
    const float* __restrict__ W1, const float* __restrict__ W2,
    const float* __restrict__ W3, const float* __restrict__ W4,
    const float* __restrict__ Wself, unsigned short* __restrict__ packed)
{
    const int t = blockIdx.x * 256 + threadIdx.x;
    if (t >= 4 * 9 * 8 * 64) return;
    const int d    = t / 4608;
    const int r    = t % 4608;
    const int ks   = r / 512;
    const int nt   = (r % 512) / 64;
    const int lane = r % 64;
    const float* Wd = (d == 0) ? W1 : (d == 1) ? W2 : (d == 2) ? W3 : W4;
    const int col = nt * 16 + (lane & 15);
    short8 v;
    #pragma unroll
    for (int j = 0; j < 8; ++j) {
        const int k = ks * 32 + ((lane >> 4) << 3) + j;
        float w = 0.f;
        if (k < 128)      w = Wself[k * 128 + col];
        else if (k < 272) w = Wd[(k - 128) * 128 + col];
        v[j] = (short)f2bf(w);
    }
    *reinterpret_cast<short8*>(packed + (size_t)d * SEG_ELEMS
                               + ((size_t)(ks * 8 + nt) * 64 + lane) * 8) = v;
}

// ---------------------------------------------------------------------------
// LDS-free per-wave loop. Lane l gathers node r=l&15, k-slice khi=l>>4:
// A fragments built directly in registers (gather IS the fragment load).
// No barriers inside the loop; bias dropped (cancels under BatchNorm).
// ---------------------------------------------------------------------------
template <int DEG>
__device__ __forceinline__ void wave_loop(
    const float* __restrict__ atom, const float* __restrict__ bond,
    const int* __restrict__ aidx, const int* __restrict__ bidx,
    const unsigned short* __restrict__ pw,
    float* __restrict__ out,
    float* __restrict__ lds_sum, float* __restrict__ lds_sq,
    int n, int lw, int nw, int lane)
{
    const int r   = lane & 15;
    const int khi = lane >> 4;

    float psum[8], psq[8];
    #pragma unroll
    for (int nt = 0; nt < 8; ++nt) { psum[nt] = 0.f; psq[nt] = 0.f; }

    const int tiles = n >> 4;       // all segment sizes % 16 == 0

    for (int ti = lw; ti < tiles; ti += nw) {
        const int i = (ti << 4) + r;

        // ---- indices for own node (all DEG+1 needed by every lane) ----
        int idxs[DEG + 1];
        {
            const int* ar = aidx + (size_t)i * (DEG + 1);
            #pragma unroll
            for (int j = 0; j <= DEG; ++j) idxs[j] = ar[j];
        }

        short8 afr[9];
        float4 acc0[4], acc1[4];
        // own row -> self frags (ks 0..3) and a_sum seed
        {
            const float* base = atom + (size_t)idxs[0] * 128 + khi * 8;
            #pragma unroll
            for (int c = 0; c < 4; ++c) {
                float4 x0 = *(const float4*)(base + c * 32);
                float4 x1 = *(const float4*)(base + c * 32 + 4);
                afr[c] = cvt8(x0, x1);
                acc0[c] = x0; acc1[c] = x1;
            }
        }
        // neighbors -> accumulate
        #pragma unroll
        for (int j = 1; j <= DEG; ++j) {
            const float* base = atom + (size_t)idxs[j] * 128 + khi * 8;
            #pragma unroll
            for (int c = 0; c < 4; ++c) {
                acc0[c] = add4(acc0[c], *(const float4*)(base + c * 32));
                acc1[c] = add4(acc1[c], *(const float4*)(base + c * 32 + 4));
            }
        }
        #pragma unroll
        for (int c = 0; c < 4; ++c) afr[4 + c] = cvt8(acc0[c], acc1[c]);

        // bonds: ks=8, khi 0/1 lanes carry b_sum cols khi*8..+7; others x0 (B=0 there)
        {
            float4 b0 = make_float4(0.f, 0.f, 0.f, 0.f), b1 = b0;
            if (khi < 2) {
                const int* br = bidx + (size_t)i * DEG;
                #pragma unroll
                for (int j = 0; j < DEG; ++j) {
                    const float* bb = bond + (size_t)br[j] * 16 + khi * 8;
                    b0 = add4(b0, *(const float4*)bb);
                    b1 = add4(b1, *(const float4*)(bb + 4));
                }
            }
            afr[8] = cvt8(b0, b1);
        }

        // own ids of the 4 C-rows this lane will store (D row = khi*4+rr)
        int owns[4];
        #pragma unroll
        for (int rr = 0; rr < 4; ++rr)
            owns[rr] = __shfl(idxs[0], khi * 4 + rr, 64);

        // ---- MFMA: 8 col-tiles, B streamed from packed (L2-resident) ----
        #pragma unroll 2
        for (int nt = 0; nt < 8; ++nt) {
            floatx4 a = (floatx4){0.f, 0.f, 0.f, 0.f};
            #pragma unroll
            for (int ks = 0; ks < 9; ++ks) {
                short8 b = ((const short8*)pw)[(ks * 8 + nt) * 64 + lane];
                a = __builtin_amdgcn_mfma_f32_16x16x32_bf16(afr[ks], b, a, 0, 0, 0);
            }
            #pragma unroll
            for (int rr = 0; rr < 4; ++rr) {
                const float v = a[rr];
                out[(size_t)owns[rr] * 128 + nt * 16 + r] = v;
                psum[nt] += v;
                psq[nt]  += v * v;
            }
        }
    }

    // ---- per-wave channel partials -> LDS (deterministic) ----
    #pragma unroll
    for (int nt = 0; nt < 8; ++nt) {
        float s = psum[nt], q = psq[nt];
        s += __shfl_xor(s, 16, 64); s += __shfl_xor(s, 32, 64);
        q += __shfl_xor(q, 16, 64); q += __shfl_xor(q, 32, 64);
        if (lane < 16) {
            lds_sum[nt * 16 + lane] = s;
            lds_sq [nt * 16 + lane] = q;
        }
    }
}

// ---------------------------------------------------------------------------
// Fused kernel: 4 independent waves per block, LDS only for final partials.
// ---------------------------------------------------------------------------
__global__ __launch_bounds__(256, 4) void gdc_mfma(
    const float* __restrict__ atom, const float* __restrict__ bond,
    const int* __restrict__ a1, const int* __restrict__ b1,
    const int* __restrict__ a2, const int* __restrict__ b2,
    const int* __restrict__ a3, const int* __restrict__ b3,
    const int* __restrict__ a4, const int* __restrict__ b4,
    const unsigned short* __restrict__ packedW,
    float* __restrict__ out,
    float* __restrict__ sumPart, float* __restrict__ sqPart)
{
    __shared__ float redS[4][128], redQ[4][128];   // 4 KB

    const int tid  = threadIdx.x;
    const int wv   = tid >> 6;
    const int lane = tid & 63;
    const int gw   = blockIdx.x * 4 + wv;

    int n, lw, nw, deg;
    const int* aidx; const int* bidx;
    if (gw < NW1)                 { deg = 1; n =  50000; lw = gw;                 nw = NW1; aidx = a1; bidx = b1; }
    else if (gw < NW1+NW2)        { deg = 2; n = 150000; lw = gw-NW1;             nw = NW2; aidx = a2; bidx = b2; }
    else if (gw < NW1+NW2+NW3)    { deg = 3; n = 200000; lw = gw-(NW1+NW2);       nw = NW3; aidx = a3; bidx = b3; }
    else                          { deg = 4; n = 100000; lw = gw-(NW1+NW2+NW3);   nw = NW4; aidx = a4; bidx = b4; }

    const unsigned short* pw = packedW + (size_t)(deg - 1) * SEG_ELEMS;

    switch (deg) {
    case 1:  wave_loop<1>(atom, bond, aidx, bidx, pw, out, redS[wv], redQ[wv], n, lw, nw, lane); break;
    case 2:  wave_loop<2>(atom, bond, aidx, bidx, pw, out, redS[wv], redQ[wv], n, lw, nw, lane); break;
    case 3:  wave_loop<3>(atom, bond, aidx, bidx, pw, out, redS[wv], redQ[wv], n, lw, nw, lane); break;
    default: wave_loop<4>(atom, bond, aidx, bidx, pw, out, redS[wv], redQ[wv], n, lw, nw, lane); break;
    }

    __syncthreads();
    // combine 4 wave partials -> per-block partials (fixed order)
    if (tid < 128) {
        sumPart[(size_t)blockIdx.x * 128 + tid] =
            redS[0][tid] + redS[1][tid] + redS[2][tid] + redS[3][tid];
    } else {
        const int c = tid - 128;
        sqPart[(size_t)blockIdx.x * 128 + c] =
            redQ[0][c] + redQ[1][c] + redQ[2][c] + redQ[3][c];
    }
}

// ---------------------------------------------------------------------------
// Reduce NBLK partials per channel -> mean, invstd (deterministic).
// ---------------------------------------------------------------------------
__global__ void gdc_stats(const float* __restrict__ sumPart,
                          const float* __restrict__ sqPart,
                          float* __restrict__ mv)
{
    const int c = blockIdx.x;
    const int j = threadIdx.x;
    __shared__ float rs[256], rq[256];
    float s = 0.f, q = 0.f;
    for (int b = j; b < NBLK; b += 256) {
        s += sumPart[(size_t)b * 128 + c];
        q += sqPart[(size_t)b * 128 + c];
    }
    rs[j] = s; rq[j] = q;
    __syncthreads();
    for (int off = 128; off > 0; off >>= 1) {
        if (j < off) { rs[j] += rs[j + off]; rq[j] += rq[j + off]; }
        __syncthreads();
    }
    if (j == 0) {
        const float mean = rs[0] / (float)N_ATOMS;
        const float var  = rq[0] / (float)N_ATOMS - mean * mean;
        mv[c]       = mean;
        mv[128 + c] = rsqrtf(var + EPS);
    }
}

// ---------------------------------------------------------------------------
// In-place normalize + ReLU. float4; per-thread channel loop-invariant.
// ---------------------------------------------------------------------------
__global__ __launch_bounds__(256) void gdc_norm(float* __restrict__ out,
                                                const float* __restrict__ mv)
{
    const size_t total4 = (size_t)N_ATOMS * 128 / 4;
    size_t idx = (size_t)blockIdx.x * 256 + threadIdx.x;
    const int c = (int)((idx * 4) & 127);
    const float4 m  = *(const float4*)(mv + c);
    const float4 iv = *(const float4*)(mv + 128 + c);
    const size_t stride = (size_t)gridDim.x * 256;
    for (; idx < total4; idx += stride) {
        float4 v = ((float4*)out)[idx];
        v.x = fmaxf(0.f, (v.x - m.x) * iv.x);
        v.y = fmaxf(0.f, (v.y - m.y) * iv.y);
        v.z = fmaxf(0.f, (v.z - m.z) * iv.z);
        v.w = fmaxf(0.f, (v.w - m.w) * iv.w);
        ((float4*)out)[idx] = v;
    }
}

extern "C" void kernel_launch(void* const* d_in, const int* in_sizes, int n_in,
                              void* d_out, int out_size, void* d_ws, size_t ws_size,
                              hipStream_t stream) {
    const float* atom  = (const float*)d_in[0];
    const float* bond  = (const float*)d_in[1];
    const int*   a1    = (const int*)d_in[2];
    const int*   b1    = (const int*)d_in[3];
    const int*   a2    = (const int*)d_in[4];
    const int*   b2    = (const int*)d_in[5];
    const int*   a3    = (const int*)d_in[6];
    const int*   b3    = (const int*)d_in[7];
    const int*   a4    = (const int*)d_in[8];
    const int*   b4    = (const int*)d_in[9];
    const float* Wself = (const float*)d_in[10];
    const float* W1    = (const float*)d_in[11];
    const float* W2    = (const float*)d_in[12];
    const float* W3    = (const float*)d_in[13];
    const float* W4    = (const float*)d_in[14];
    // bias cancels under BatchNorm (shift-invariance) -> not used
    float* out = (float*)d_out;

    // ws layout: packedW (294912 B) | sumPart[NBLK*128] | sqPart[NBLK*128] | mv[256]
    unsigned short* packedW = (unsigned short*)d_ws;
    float* sumPart = (float*)((char*)d_ws + 4 * SEG_ELEMS * sizeof(unsigned short));
    float* sqPart  = sumPart + (size_t)NBLK * 128;
    float* mv      = sqPart + (size_t)NBLK * 128;

    hipLaunchKernelGGL(gdc_pack, dim3((4*9*8*64 + 255)/256), dim3(256), 0, stream,
                       W1, W2, W3, W4, Wself, packedW);
    hipLaunchKernelGGL(gdc_mfma, dim3(NBLK), dim3(256), 0, stream,
                       atom, bond, a1, b1, a2, b2, a3, b3, a4, b4,
                       packedW, out, sumPart, sqPart);
    hipLaunchKernelGGL(gdc_stats, dim3(128), dim3(256), 0, stream,
                       sumPart, sqPart, mv);
    hipLaunchKernelGGL(gdc_norm, dim3(2048), dim3(256), 0, stream, out, mv);
}

// Round 6
// 461.809 us; speedup vs baseline: 1.3580x; 1.3580x over previous
//
#include <hip/hip_runtime.h>
#include <hip/hip_bf16.h>
#include <math.h>

#define N_ATOMS 500000
#define EPS 1e-5f
#define LDA 296   // bf16 elems per A row: 288 + 8 pad (breaks bank aliasing)

// wave counts per degree segment (total 4096 waves = 1024 blocks x 4 waves),
// proportional to gather volume n_d*(d+1) -> equal work per wave
#define NW1 221
#define NW2 997
#define NW3 1771
#define NW4 1107
#define TOTW 4096
#define NBLK 1024

#define SEG_ELEMS 36864   // 288*128 bf16 per packed weight segment

typedef __attribute__((ext_vector_type(8))) short short8;
typedef __attribute__((ext_vector_type(4))) float floatx4;

__device__ __forceinline__ unsigned short f2bf(float f) {
    unsigned int x = __float_as_uint(f);
    x += 0x7FFF + ((x >> 16) & 1);          // round-to-nearest-even
    return (unsigned short)(x >> 16);
}

__device__ __forceinline__ float4 add4(float4 a, float4 b) {
    return make_float4(a.x + b.x, a.y + b.y, a.z + b.z, a.w + b.w);
}

__device__ __forceinline__ void st_bf4(unsigned short* p, float4 v) {
    ushort4 u;
    u.x = f2bf(v.x); u.y = f2bf(v.y); u.z = f2bf(v.z); u.w = f2bf(v.w);
    *reinterpret_cast<ushort4*>(p) = u;     // ds_write_b64
}

// ---------------------------------------------------------------------------
// Pack weights into MFMA B-fragment layout, bf16.
// packed[d]: (ks 0..8, nt 0..7, lane 0..63) -> short8; col = nt*16+(lane&15),
// k = ks*32 + (lane>>4)*8 + j; k<144 -> W_d, k<272 -> W_self, else 0.
// ---------------------------------------------------------------------------
__global__ __launch_bounds__(256) void gdc_pack(
    const float* __restrict__ W1, const float* __restrict__ W2,
    const float* __restrict__ W3, const float* __restrict__ W4,
    const float* __restrict__ Wself, unsigned short* __restrict__ packed)
{
    const int t = blockIdx.x * 256 + threadIdx.x;
    if (t >= 4 * 9 * 8 * 64) return;
    const int d    = t / 4608;
    const int r    = t % 4608;
    const int ks   = r / 512;
    const int nt   = (r % 512) / 64;
    const int lane = r % 64;
    const float* Wd = (d == 0) ? W1 : (d == 1) ? W2 : (d == 2) ? W3 : W4;
    const int col = nt * 16 + (lane & 15);
    short8 v;
    #pragma unroll
    for (int j = 0; j < 8; ++j) {
        const int k = ks * 32 + ((lane >> 4) << 3) + j;
        float w = 0.f;
        if (k < 144)      w = Wd[k * 128 + col];
        else if (k < 272) w = Wself[(k - 144) * 128 + col];
        v[j] = (short)f2bf(w);
    }
    *reinterpret_cast<short8*>(packed + (size_t)d * SEG_ELEMS
                               + ((size_t)(ks * 8 + nt) * 64 + lane) * 8) = v;
}

// ---------------------------------------------------------------------------
// Per-wave tile loop, templated on degree (wave-uniform -> full unroll of
// neighbor gathers). One wave owns a private 16-row A tile; NO barriers.
// ---------------------------------------------------------------------------
template <int DEG>
__device__ __forceinline__ void wave_loop(
    const float* __restrict__ atom, const float* __restrict__ bond,
    const int* __restrict__ aidx, const int* __restrict__ bidx,
    const unsigned short* __restrict__ pw, const float* __restrict__ bias,
    float* __restrict__ out,
    unsigned short* __restrict__ A, int* __restrict__ own_w,
    int n, int lw, int nw, int lane)
{
    const int m8   = lane >> 3, q8 = lane & 7;   // atom gather: 8 nodes x 8 k-slices
    const int mb   = lane >> 2, qb = lane & 3;   // bond gather: 16 nodes x 4 slices
    const int crow = lane >> 4;                  // C row group
    const int ccol = lane & 15;                  // C col within 16-tile / A row

    float bias_r[8];
    #pragma unroll
    for (int nt = 0; nt < 8; ++nt) bias_r[nt] = bias[nt * 16 + ccol];

    float psum[8], psq[8];
    #pragma unroll
    for (int nt = 0; nt < 8; ++nt) { psum[nt] = 0.f; psq[nt] = 0.f; }

    const int tiles = n >> 4;                    // all segment sizes % 16 == 0

    for (int ti = lw; ti < tiles; ti += nw) {
        const int i0 = ti << 4;

        // ---- atom gather: 2 sub-passes of 8 nodes, 16 floats/lane ----
        #pragma unroll
        for (int sp = 0; sp < 2; ++sp) {
            const int m = sp * 8 + m8;
            const int i = i0 + m;
            const int* ar = aidx + (size_t)i * (DEG + 1);
            const int own = ar[0];
            if (q8 == 0) own_w[m] = own;
            const float4* s = (const float4*)(atom + (size_t)own * 128 + q8 * 16);
            float4 a0 = s[0], a1 = s[1], a2 = s[2], a3 = s[3];
            unsigned short* rowp = A + m * LDA;
            // self slice -> cols 144 + q8*16
            st_bf4(rowp + 144 + q8 * 16 + 0,  a0);
            st_bf4(rowp + 144 + q8 * 16 + 4,  a1);
            st_bf4(rowp + 144 + q8 * 16 + 8,  a2);
            st_bf4(rowp + 144 + q8 * 16 + 12, a3);
            #pragma unroll
            for (int j = 1; j <= DEG; ++j) {
                const float4* p = (const float4*)(atom + (size_t)ar[j] * 128 + q8 * 16);
                a0 = add4(a0, p[0]); a1 = add4(a1, p[1]);
                a2 = add4(a2, p[2]); a3 = add4(a3, p[3]);
            }
            st_bf4(rowp + q8 * 16 + 0,  a0);
            st_bf4(rowp + q8 * 16 + 4,  a1);
            st_bf4(rowp + q8 * 16 + 8,  a2);
            st_bf4(rowp + q8 * 16 + 12, a3);
        }
        // ---- bond gather: 16 nodes x 4 floats/lane + zero K-pad ----
        {
            const int i = i0 + mb;
            const int* br = bidx + (size_t)i * DEG;
            float4 b = make_float4(0.f, 0.f, 0.f, 0.f);
            #pragma unroll
            for (int j = 0; j < DEG; ++j)
                b = add4(b, *(const float4*)(bond + (size_t)br[j] * 16 + qb * 4));
            st_bf4(A + mb * LDA + 128 + qb * 4, b);
            ushort4 z; z.x = z.y = z.z = z.w = 0;
            *reinterpret_cast<ushort4*>(A + mb * LDA + 272 + qb * 4) = z;
        }

        // wave-private LDS: drain writes, then fragment reads (no barrier)
        asm volatile("s_waitcnt lgkmcnt(0)" ::: "memory");
        __builtin_amdgcn_sched_barrier(0);

        short8 afr[9];
        #pragma unroll
        for (int ks = 0; ks < 9; ++ks)
            afr[ks] = *(const short8*)&A[ccol * LDA + ks * 32 + (crow << 3)];
        const int4 ownr = *reinterpret_cast<const int4*>(&own_w[crow * 4]);
        const int owns[4] = {ownr.x, ownr.y, ownr.z, ownr.w};

        // ---- MFMA: 8 col-tiles, B streamed from packed (L2-resident) ----
        #pragma unroll 2
        for (int nt = 0; nt < 8; ++nt) {
            short8 bfr[9];
            #pragma unroll
            for (int ks = 0; ks < 9; ++ks)
                bfr[ks] = ((const short8*)pw)[(ks * 8 + nt) * 64 + lane];
            floatx4 acc = (floatx4){0.f, 0.f, 0.f, 0.f};
            #pragma unroll
            for (int ks = 0; ks < 9; ++ks)
                acc = __builtin_amdgcn_mfma_f32_16x16x32_bf16(afr[ks], bfr[ks], acc, 0, 0, 0);
            #pragma unroll
            for (int r = 0; r < 4; ++r) {
                const float v = acc[r] + bias_r[nt];
                out[(size_t)owns[r] * 128 + nt * 16 + ccol] = v;
                psum[nt] += v;
                psq[nt]  += v * v;
            }
        }
    }

    // ---- per-wave channel partials -> wave's own A-tile LDS (now dead) ----
    float* red = reinterpret_cast<float*>(A);   // 128 sum | 128 sq
    #pragma unroll
    for (int nt = 0; nt < 8; ++nt) {
        float s = psum[nt], q = psq[nt];
        s += __shfl_xor(s, 16, 64); s += __shfl_xor(s, 32, 64);
        q += __shfl_xor(q, 16, 64); q += __shfl_xor(q, 32, 64);
        if (lane < 16) {
            red[nt * 16 + lane]       = s;
            red[128 + nt * 16 + lane] = q;
        }
    }
}

// ---------------------------------------------------------------------------
// Fused kernel: 4 independent waves per block, each with a private A tile.
// After the loop, the A tiles are reused as the BN-partial reduction buffer.
// ---------------------------------------------------------------------------
__global__ __launch_bounds__(256, 4) void gdc_mfma(
    const float* __restrict__ atom, const float* __restrict__ bond,
    const int* __restrict__ a1, const int* __restrict__ b1,
    const int* __restrict__ a2, const int* __restrict__ b2,
    const int* __restrict__ a3, const int* __restrict__ b3,
    const int* __restrict__ a4, const int* __restrict__ b4,
    const unsigned short* __restrict__ packedW, const float* __restrict__ bias,
    float* __restrict__ out,
    float* __restrict__ sumPart, float* __restrict__ sqPart)
{
    __shared__ __align__(16) unsigned short A_all[4][16 * LDA];  // 37888 B
    __shared__ __align__(16) int own_all[4][16];

    const int tid  = threadIdx.x;
    const int wv   = tid >> 6;
    const int lane = tid & 63;
    const int gw   = blockIdx.x * 4 + wv;

    unsigned short* A = A_all[wv];
    int* own_w = own_all[wv];

    int n, lw, nw, deg;
    const int* aidx; const int* bidx;
    if (gw < NW1)                 { deg = 1; n =  50000; lw = gw;                 nw = NW1; aidx = a1; bidx = b1; }
    else if (gw < NW1+NW2)        { deg = 2; n = 150000; lw = gw-NW1;             nw = NW2; aidx = a2; bidx = b2; }
    else if (gw < NW1+NW2+NW3)    { deg = 3; n = 200000; lw = gw-(NW1+NW2);       nw = NW3; aidx = a3; bidx = b3; }
    else                          { deg = 4; n = 100000; lw = gw-(NW1+NW2+NW3);   nw = NW4; aidx = a4; bidx = b4; }

    const unsigned short* pw = packedW + (size_t)(deg - 1) * SEG_ELEMS;

    switch (deg) {
    case 1:  wave_loop<1>(atom, bond, aidx, bidx, pw, bias, out, A, own_w, n, lw, nw, lane); break;
    case 2:  wave_loop<2>(atom, bond, aidx, bidx, pw, bias, out, A, own_w, n, lw, nw, lane); break;
    case 3:  wave_loop<3>(atom, bond, aidx, bidx, pw, bias, out, A, own_w, n, lw, nw, lane); break;
    default: wave_loop<4>(atom, bond, aidx, bidx, pw, bias, out, A, own_w, n, lw, nw, lane); break;
    }

    __syncthreads();
    // combine 4 wave partials -> per-block partials (fixed order)
    if (tid < 128) {
        float s = 0.f;
        #pragma unroll
        for (int w = 0; w < 4; ++w)
            s += reinterpret_cast<const float*>(A_all[w])[tid];
        sumPart[(size_t)blockIdx.x * 128 + tid] = s;
    } else {
        const int c = tid - 128;
        float q = 0.f;
        #pragma unroll
        for (int w = 0; w < 4; ++w)
            q += reinterpret_cast<const float*>(A_all[w])[128 + c];
        sqPart[(size_t)blockIdx.x * 128 + c] = q;
    }
}

// ---------------------------------------------------------------------------
// Reduce NBLK partials per channel -> mean, invstd (deterministic).
// ---------------------------------------------------------------------------
__global__ void gdc_stats(const float* __restrict__ sumPart,
                          const float* __restrict__ sqPart,
                          float* __restrict__ mv)
{
    const int c = blockIdx.x;
    const int j = threadIdx.x;
    __shared__ float rs[256], rq[256];
    float s = 0.f, q = 0.f;
    for (int b = j; b < NBLK; b += 256) {
        s += sumPart[(size_t)b * 128 + c];
        q += sqPart[(size_t)b * 128 + c];
    }
    rs[j] = s; rq[j] = q;
    __syncthreads();
    for (int off = 128; off > 0; off >>= 1) {
        if (j < off) { rs[j] += rs[j + off]; rq[j] += rq[j + off]; }
        __syncthreads();
    }
    if (j == 0) {
        const float mean = rs[0] / (float)N_ATOMS;
        const float var  = rq[0] / (float)N_ATOMS - mean * mean;
        mv[c]       = mean;
        mv[128 + c] = rsqrtf(var + EPS);
    }
}

// ---------------------------------------------------------------------------
// In-place normalize + ReLU. float4; per-thread channel loop-invariant.
// ---------------------------------------------------------------------------
__global__ __launch_bounds__(256) void gdc_norm(float* __restrict__ out,
                                                const float* __restrict__ mv)
{
    const size_t total4 = (size_t)N_ATOMS * 128 / 4;
    size_t idx = (size_t)blockIdx.x * 256 + threadIdx.x;
    const int c = (int)((idx * 4) & 127);
    const float4 m  = *(const float4*)(mv + c);
    const float4 iv = *(const float4*)(mv + 128 + c);
    const size_t stride = (size_t)gridDim.x * 256;
    for (; idx < total4; idx += stride) {
        float4 v = ((float4*)out)[idx];
        v.x = fmaxf(0.f, (v.x - m.x) * iv.x);
        v.y = fmaxf(0.f, (v.y - m.y) * iv.y);
        v.z = fmaxf(0.f, (v.z - m.z) * iv.z);
        v.w = fmaxf(0.f, (v.w - m.w) * iv.w);
        ((float4*)out)[idx] = v;
    }
}

extern "C" void kernel_launch(void* const* d_in, const int* in_sizes, int n_in,
                              void* d_out, int out_size, void* d_ws, size_t ws_size,
                              hipStream_t stream) {
    const float* atom  = (const float*)d_in[0];
    const float* bond  = (const float*)d_in[1];
    const int*   a1    = (const int*)d_in[2];
    const int*   b1    = (const int*)d_in[3];
    const int*   a2    = (const int*)d_in[4];
    const int*   b2    = (const int*)d_in[5];
    const int*   a3    = (const int*)d_in[6];
    const int*   b3    = (const int*)d_in[7];
    const int*   a4    = (const int*)d_in[8];
    const int*   b4    = (const int*)d_in[9];
    const float* Wself = (const float*)d_in[10];
    const float* W1    = (const float*)d_in[11];
    const float* W2    = (const float*)d_in[12];
    const float* W3    = (const float*)d_in[13];
    const float* W4    = (const float*)d_in[14];
    const float* bias  = (const float*)d_in[15];
    float* out = (float*)d_out;

    // ws layout: packedW (294912 B) | sumPart[NBLK*128] | sqPart[NBLK*128] | mv[256]
    unsigned short* packedW = (unsigned short*)d_ws;
    float* sumPart = (float*)((char*)d_ws + 4 * SEG_ELEMS * sizeof(unsigned short));
    float* sqPart  = sumPart + (size_t)NBLK * 128;
    float* mv      = sqPart + (size_t)NBLK * 128;

    hipLaunchKernelGGL(gdc_pack, dim3((4*9*8*64 + 255)/256), dim3(256), 0, stream,
                       W1, W2, W3, W4, Wself, packedW);
    hipLaunchKernelGGL(gdc_mfma, dim3(NBLK), dim3(256), 0, stream,
                       atom, bond, a1, b1, a2, b2, a3, b3, a4, b4,
                       packedW, bias, out, sumPart, sqPart);
    hipLaunchKernelGGL(gdc_stats, dim3(128), dim3(256), 0, stream,
                       sumPart, sqPart, mv);
    hipLaunchKernelGGL(gdc_norm, dim3(2048), dim3(256), 0, stream, out, mv);
}